// Round 4
// baseline (629.154 us; speedup 1.0000x reference)
//
#include <hip/hip_runtime.h>
#include <math.h>

// Problem constants: B=4, H=8, L=512, HD=64, D=512, RHO=0.1
// Workspace (floats):
//   Q   : 1M   [BH][512][64]
//   Kt  : 1M
//   V   : 1M
//   S   : 8M   [BH][512][512]  (scores -> later J -> softmax'd P)
//   Am  : 8M   (adjacency -> A_hat in place)
//   T   : 8M   (A_hat@S temp)
//   R   : 16K  (row inv-sqrt degrees)
//   O   : 1M

typedef __attribute__((ext_vector_type(8))) short short8v;
typedef __attribute__((ext_vector_type(4))) float f32x4;

// ---------------------------------------------------------------------------
// Generic 128x128-tile fp32 GEMM, BK=16, 256 threads, 8x8 micro-tile.
// BT=1: C = A * B^T. BT=0: C = A * B.
// ---------------------------------------------------------------------------
template<int BT>
__global__ __launch_bounds__(256)
void gemm128(const float* __restrict__ Ap, const float* __restrict__ Bp,
             float* __restrict__ Cp, int M, int N, int K,
             long sA, long sB, long sC, float scale)
{
    const float* A  = Ap + (long)blockIdx.z * sA;
    const float* Bm = Bp + (long)blockIdx.z * sB;
    float*       C  = Cp + (long)blockIdx.z * sC;

    __shared__ float As[16][132];
    __shared__ float Bs[16][132];

    const int tid = threadIdx.x;
    const int tx = tid & 15, ty = tid >> 4;
    const int m0 = blockIdx.y << 7, n0 = blockIdx.x << 7;

    float acc[8][8] = {};

    for (int k0 = 0; k0 < K; k0 += 16) {
        const int r = tid >> 1, c = (tid & 1) << 3;
        float4 a0 = *(const float4*)(A + (long)(m0 + r) * K + k0 + c);
        float4 a1 = *(const float4*)(A + (long)(m0 + r) * K + k0 + c + 4);
        float4 b0, b1;
        int rb = 0, cb = 0;
        if (BT) {
            b0 = *(const float4*)(Bm + (long)(n0 + r) * K + k0 + c);
            b1 = *(const float4*)(Bm + (long)(n0 + r) * K + k0 + c + 4);
        } else {
            rb = tid >> 4; cb = (tid & 15) << 3;
            b0 = *(const float4*)(Bm + (long)(k0 + rb) * N + n0 + cb);
            b1 = *(const float4*)(Bm + (long)(k0 + rb) * N + n0 + cb + 4);
        }

        As[c + 0][r] = a0.x; As[c + 1][r] = a0.y; As[c + 2][r] = a0.z; As[c + 3][r] = a0.w;
        As[c + 4][r] = a1.x; As[c + 5][r] = a1.y; As[c + 6][r] = a1.z; As[c + 7][r] = a1.w;
        if (BT) {
            Bs[c + 0][r] = b0.x; Bs[c + 1][r] = b0.y; Bs[c + 2][r] = b0.z; Bs[c + 3][r] = b0.w;
            Bs[c + 4][r] = b1.x; Bs[c + 5][r] = b1.y; Bs[c + 6][r] = b1.z; Bs[c + 7][r] = b1.w;
        } else {
            *(float4*)&Bs[rb][cb]     = b0;
            *(float4*)&Bs[rb][cb + 4] = b1;
        }
        __syncthreads();

        #pragma unroll
        for (int kk = 0; kk < 16; ++kk) {
            float a[8], b[8];
            *(float4*)&a[0] = *(const float4*)&As[kk][ty << 3];
            *(float4*)&a[4] = *(const float4*)&As[kk][(ty << 3) + 4];
            *(float4*)&b[0] = *(const float4*)&Bs[kk][tx << 3];
            *(float4*)&b[4] = *(const float4*)&Bs[kk][(tx << 3) + 4];
            #pragma unroll
            for (int i = 0; i < 8; ++i)
                #pragma unroll
                for (int j = 0; j < 8; ++j)
                    acc[i][j] = fmaf(a[i], b[j], acc[i][j]);
        }
        __syncthreads();
    }

    #pragma unroll
    for (int i = 0; i < 8; ++i) {
        const int m = m0 + (ty << 3) + i;
        #pragma unroll
        for (int j4 = 0; j4 < 8; j4 += 4) {
            float4 v = make_float4(acc[i][j4 + 0] * scale, acc[i][j4 + 1] * scale,
                                   acc[i][j4 + 2] * scale, acc[i][j4 + 3] * scale);
            *(float4*)(C + (long)m * N + n0 + (tx << 3) + j4) = v;
        }
    }
}

// ---------------------------------------------------------------------------
// Fused QKV projection: x[2048x512] x {Wq|Wk|Wv}[512x512] -> [BH][512][64] x3
// ---------------------------------------------------------------------------
__global__ __launch_bounds__(256)
void gemm_qkv(const float* __restrict__ x, const float* __restrict__ Wq,
              const float* __restrict__ Wk, const float* __restrict__ Wv,
              float* __restrict__ QKV)
{
    const int m0 = blockIdx.y << 7;
    const int ng = blockIdx.x << 7;
    const float* W = (ng < 512) ? Wq : (ng < 1024) ? Wk : Wv;
    const int n0 = ng & 511;
    float* C = QKV + (long)(ng >> 9) * (1 << 20);

    __shared__ float As[16][132];
    __shared__ float Bs[16][132];

    const int tid = threadIdx.x;
    const int tx = tid & 15, ty = tid >> 4;

    float acc[8][8] = {};

    for (int k0 = 0; k0 < 512; k0 += 16) {
        const int r = tid >> 1, c = (tid & 1) << 3;
        float4 a0 = *(const float4*)(x + (long)(m0 + r) * 512 + k0 + c);
        float4 a1 = *(const float4*)(x + (long)(m0 + r) * 512 + k0 + c + 4);
        const int rb = tid >> 4, cb = (tid & 15) << 3;
        float4 b0 = *(const float4*)(W + (long)(k0 + rb) * 512 + n0 + cb);
        float4 b1 = *(const float4*)(W + (long)(k0 + rb) * 512 + n0 + cb + 4);

        As[c + 0][r] = a0.x; As[c + 1][r] = a0.y; As[c + 2][r] = a0.z; As[c + 3][r] = a0.w;
        As[c + 4][r] = a1.x; As[c + 5][r] = a1.y; As[c + 6][r] = a1.z; As[c + 7][r] = a1.w;
        *(float4*)&Bs[rb][cb]     = b0;
        *(float4*)&Bs[rb][cb + 4] = b1;
        __syncthreads();

        #pragma unroll
        for (int kk = 0; kk < 16; ++kk) {
            float a[8], b[8];
            *(float4*)&a[0] = *(const float4*)&As[kk][ty << 3];
            *(float4*)&a[4] = *(const float4*)&As[kk][(ty << 3) + 4];
            *(float4*)&b[0] = *(const float4*)&Bs[kk][tx << 3];
            *(float4*)&b[4] = *(const float4*)&Bs[kk][(tx << 3) + 4];
            #pragma unroll
            for (int i = 0; i < 8; ++i)
                #pragma unroll
                for (int j = 0; j < 8; ++j)
                    acc[i][j] = fmaf(a[i], b[j], acc[i][j]);
        }
        __syncthreads();
    }

    #pragma unroll
    for (int i = 0; i < 8; ++i) {
        const int m = m0 + (ty << 3) + i;
        const int b = m >> 9, l = m & 511;
        #pragma unroll
        for (int j4 = 0; j4 < 8; j4 += 4) {
            const int nl = n0 + (tx << 3) + j4;
            const int h = nl >> 6, d = nl & 63;
            float4 v = make_float4(acc[i][j4 + 0], acc[i][j4 + 1],
                                   acc[i][j4 + 2], acc[i][j4 + 3]);
            *(float4*)(C + ((long)((b * 8 + h) * 512 + l)) * 64 + d) = v;
        }
    }
}

// ---------------------------------------------------------------------------
// Adjacency v3: A[i,k] = (1/512) sum_j u, u = S_ij*S_kj/64 if > 0.1, diag 0.
// Equivalent raw form: acc += (p = S_ij*S_kj) if p > 0.1*64; A = acc * 2^-15.
// (pow2 scaling commutes with fp rounding -> bit-identical to reference.)
// 64x64 tile per block, upper-triangle tile pairs (36/64), mirrored write.
// Block = 2 waves; wave w sums j in [256w, 256w+256): private LDS staging,
// NO barriers in main loop. 8x8 micro-tile per lane (64 indep chains).
// Register-double-buffered global loads hide HBM/L2 latency under compute.
// ---------------------------------------------------------------------------
__global__ __launch_bounds__(128)
void adj_kernel(const float* __restrict__ S, float* __restrict__ A)
{
    const int bh = blockIdx.y;
    const float* __restrict__ Sh = S + (long)bh * 262144;
    float* __restrict__ Ah = A + (long)bh * 262144;

    // upper-triangle tile pair: blockIdx.x in [0,36) -> (ti <= tk)
    int ti = 0, rem = blockIdx.x;
    while (rem >= 8 - ti) { rem -= 8 - ti; ++ti; }
    const int tk = ti + rem;
    const int i0 = ti << 6, k0 = tk << 6;

    __shared__ float smem[4352];                 // 17408 B
    // staging view: [wave*2 + (L=0/R=1)][j(16)][row 64 + pad 4]
    float (*stg)[16][68] = (float(*)[16][68])smem;
    // reduce view (aliased, used after all compute):
    float (*red)[68] = (float(*)[68])smem;       // [64][68]

    const int tid  = threadIdx.x;
    const int lane = tid & 63;
    const int wv   = tid >> 6;                   // 0 or 1: j-half
    const int ly8  = (lane >> 3) << 3;           // i-octet base
    const int lx8  = (lane & 7) << 3;            // k-octet base

    const int r4 = lane >> 2;                    // staging row group
    const int q  = lane & 3;                     // staging j-quad

    float (*stgL)[68] = stg[wv * 2 + 0];
    float (*stgR)[68] = stg[wv * 2 + 1];

    const float RHO64 = 0.1f * 64.0f;            // exact: 0x40CCCCCD

    float acc[8][8] = {};
    float4 rl[4], rr[4];

    // prologue loads (chunk 0)
    {
        const int j0 = (wv << 8);
        #pragma unroll
        for (int p = 0; p < 4; ++p) {
            rl[p] = *(const float4*)(Sh + (long)(i0 + r4 + p * 16) * 512 + j0 + (q << 2));
            rr[p] = *(const float4*)(Sh + (long)(k0 + r4 + p * 16) * 512 + j0 + (q << 2));
        }
    }

    for (int c = 0; c < 16; ++c) {
        // ds-write staged regs (transposed: [j][row])
        #pragma unroll
        for (int p = 0; p < 4; ++p) {
            const int row = r4 + p * 16;
            stgL[(q << 2) + 0][row] = rl[p].x;
            stgL[(q << 2) + 1][row] = rl[p].y;
            stgL[(q << 2) + 2][row] = rl[p].z;
            stgL[(q << 2) + 3][row] = rl[p].w;
            stgR[(q << 2) + 0][row] = rr[p].x;
            stgR[(q << 2) + 1][row] = rr[p].y;
            stgR[(q << 2) + 2][row] = rr[p].z;
            stgR[(q << 2) + 3][row] = rr[p].w;
        }
        // issue next chunk's global loads (land during compute below)
        if (c < 15) {
            const int j0 = (wv << 8) + ((c + 1) << 4);
            #pragma unroll
            for (int p = 0; p < 4; ++p) {
                rl[p] = *(const float4*)(Sh + (long)(i0 + r4 + p * 16) * 512 + j0 + (q << 2));
                rr[p] = *(const float4*)(Sh + (long)(k0 + r4 + p * 16) * 512 + j0 + (q << 2));
            }
        }
        // compute 16 j's against 8x8 micro-tile
        #pragma unroll 4
        for (int jj = 0; jj < 16; ++jj) {
            float a[8], b[8];
            *(float4*)&a[0] = *(const float4*)&stgL[jj][ly8];
            *(float4*)&a[4] = *(const float4*)&stgL[jj][ly8 + 4];
            *(float4*)&b[0] = *(const float4*)&stgR[jj][lx8];
            *(float4*)&b[4] = *(const float4*)&stgR[jj][lx8 + 4];
            #pragma unroll
            for (int i = 0; i < 8; ++i)
                #pragma unroll
                for (int j = 0; j < 8; ++j) {
                    const float u = a[i] * b[j];
                    if (u > RHO64) acc[i][j] += u;
                }
        }
    }

    __syncthreads();            // all compute done (staging buffers now free)

    if (wv == 0) {
        // dump wave0 partials into red[lane][0..63]
        #pragma unroll
        for (int i = 0; i < 8; ++i) {
            *(float4*)&red[lane][i * 8]     = *(float4*)&acc[i][0];
            *(float4*)&red[lane][i * 8 + 4] = *(float4*)&acc[i][4];
        }
    }
    __syncthreads();

    if (wv == 1) {
        const float SC = 1.0f / 32768.0f;   // 2^-15 = (1/64)*(1/512), exact
        float f[8][8];
        #pragma unroll
        for (int i = 0; i < 8; ++i) {
            float4 p0 = *(float4*)&red[lane][i * 8];
            float4 p1 = *(float4*)&red[lane][i * 8 + 4];
            f[i][0] = (acc[i][0] + p0.x) * SC;
            f[i][1] = (acc[i][1] + p0.y) * SC;
            f[i][2] = (acc[i][2] + p0.z) * SC;
            f[i][3] = (acc[i][3] + p0.w) * SC;
            f[i][4] = (acc[i][4] + p1.x) * SC;
            f[i][5] = (acc[i][5] + p1.y) * SC;
            f[i][6] = (acc[i][6] + p1.z) * SC;
            f[i][7] = (acc[i][7] + p1.w) * SC;
        }
        if (ti == tk) {
            #pragma unroll
            for (int i = 0; i < 8; ++i)
                #pragma unroll
                for (int j = 0; j < 8; ++j)
                    if (ly8 + i == lx8 + j) f[i][j] = 0.0f;
        }
        // direct tile write: row gi, cols k0+lx8 .. +8
        #pragma unroll
        for (int i = 0; i < 8; ++i) {
            float* dst = Ah + (long)(i0 + ly8 + i) * 512 + k0 + lx8;
            *(float4*)dst       = make_float4(f[i][0], f[i][1], f[i][2], f[i][3]);
            *(float4*)(dst + 4) = make_float4(f[i][4], f[i][5], f[i][6], f[i][7]);
        }
        // mirror tile write (transposed), skip on diagonal tiles
        if (ti != tk) {
            #pragma unroll
            for (int j = 0; j < 8; ++j) {
                float* dst = Ah + (long)(k0 + lx8 + j) * 512 + i0 + ly8;
                *(float4*)dst       = make_float4(f[0][j], f[1][j], f[2][j], f[3][j]);
                *(float4*)(dst + 4) = make_float4(f[4][j], f[5][j], f[6][j], f[7][j]);
            }
        }
    }
}

// ---------------------------------------------------------------------------
// Row degree: R[row] = 1/sqrt(clip(1 + sum_k A[row,k], 1e-6))
// ---------------------------------------------------------------------------
__global__ __launch_bounds__(256)
void rowsum_kernel(const float* __restrict__ A, float* __restrict__ R)
{
    const int row = (blockIdx.x << 2) + (threadIdx.x >> 6);
    const int lane = threadIdx.x & 63;
    const float* p = A + (long)row * 512;
    float s = 0.0f;
    #pragma unroll
    for (int t = 0; t < 8; ++t) s += p[lane + (t << 6)];
    #pragma unroll
    for (int off = 32; off; off >>= 1) s += __shfl_xor(s, off, 64);
    if (lane == 0) R[row] = 1.0f / sqrtf(fmaxf(1.0f + s, 1e-6f));
}

// ---------------------------------------------------------------------------
// A_hat[i,k] = R[i]*R[k]*(A[i,k] + (i==k)) in place
// ---------------------------------------------------------------------------
__global__ __launch_bounds__(256)
void ahat_kernel(float* __restrict__ A, const float* __restrict__ R)
{
    const long i4 = ((long)blockIdx.x * 256 + threadIdx.x) << 2;
    const long off = i4 & 262143;
    const long bh = i4 >> 18;
    const int i = (int)(off >> 9);
    const int k = (int)(off & 511);
    const float ri = R[(bh << 9) + i];
    const float* Rk = R + (bh << 9) + k;
    float4 v = *(float4*)(A + i4);
    v.x = ri * Rk[0] * (v.x + ((k + 0) == i ? 1.0f : 0.0f));
    v.y = ri * Rk[1] * (v.y + ((k + 1) == i ? 1.0f : 0.0f));
    v.z = ri * Rk[2] * (v.z + ((k + 2) == i ? 1.0f : 0.0f));
    v.w = ri * Rk[3] * (v.w + ((k + 3) == i ? 1.0f : 0.0f));
    *(float4*)(A + i4) = v;
}

// ---------------------------------------------------------------------------
// Split-bf16 MFMA GEMM, per-head batched 512x512x512.
// BT=0: C = A @ B; BT=1: C = A @ B^T. acc = Ahi*Bhi + Ahi*Blo + Alo*Bhi.
// ---------------------------------------------------------------------------
template<int BT>
__global__ __launch_bounds__(256)
void gemm_mfma(const float* __restrict__ Ap, const float* __restrict__ Bp,
               float* __restrict__ Cp, float scale)
{
    const int bh = blockIdx.z;
    const float* __restrict__ A = Ap + (long)bh * 262144;
    const float* __restrict__ B = Bp + (long)bh * 262144;
    float* __restrict__ C = Cp + (long)bh * 262144;
    const int m0 = blockIdx.y << 7, n0 = blockIdx.x << 7;

    __shared__ short Ah[128 * 32], Al[128 * 32], Bh[128 * 32], Bl[128 * 32];

    const int tid = threadIdx.x;
    const int lane = tid & 63, wv = tid >> 6;
    const int wr = wv >> 1, wc = wv & 1;

    f32x4 acc[4][4] = {};

    for (int k0 = 0; k0 < 512; k0 += 32) {
        {
            const int row = tid >> 1;
            const int swz = (row & 3) ^ ((row >> 2) & 3);
            #pragma unroll
            for (int gg = 0; gg < 2; ++gg) {
                const int g = ((tid & 1) << 1) + gg;
                const float* src = A + (long)(m0 + row) * 512 + k0 + (g << 3);
                float v[8];
                *(float4*)&v[0] = *(const float4*)src;
                *(float4*)&v[4] = *(const float4*)(src + 4);
                unsigned hi[4], lo[4];
                #pragma unroll
                for (int qq = 0; qq < 4; ++qq) {
                    const unsigned b0 = __float_as_uint(v[2 * qq])     & 0xFFFF0000u;
                    const unsigned b1 = __float_as_uint(v[2 * qq + 1]) & 0xFFFF0000u;
                    const float d0 = v[2 * qq]     - __uint_as_float(b0);
                    const float d1 = v[2 * qq + 1] - __uint_as_float(b1);
                    hi[qq] = (b0 >> 16) | b1;
                    lo[qq] = (__float_as_uint(d0) >> 16) | (__float_as_uint(d1) & 0xFFFF0000u);
                }
                const int off = row * 32 + ((g ^ swz) << 3);
                *(uint4*)&Ah[off] = *(uint4*)hi;
                *(uint4*)&Al[off] = *(uint4*)lo;
            }
        }
        if (BT) {
            const int row = tid >> 1;
            const int swz = (row & 3) ^ ((row >> 2) & 3);
            #pragma unroll
            for (int gg = 0; gg < 2; ++gg) {
                const int g = ((tid & 1) << 1) + gg;
                const float* src = B + (long)(n0 + row) * 512 + k0 + (g << 3);
                float v[8];
                *(float4*)&v[0] = *(const float4*)src;
                *(float4*)&v[4] = *(const float4*)(src + 4);
                unsigned hi[4], lo[4];
                #pragma unroll
                for (int qq = 0; qq < 4; ++qq) {
                    const unsigned b0 = __float_as_uint(v[2 * qq])     & 0xFFFF0000u;
                    const unsigned b1 = __float_as_uint(v[2 * qq + 1]) & 0xFFFF0000u;
                    const float d0 = v[2 * qq]     - __uint_as_float(b0);
                    const float d1 = v[2 * qq + 1] - __uint_as_float(b1);
                    hi[qq] = (b0 >> 16) | b1;
                    lo[qq] = (__float_as_uint(d0) >> 16) | (__float_as_uint(d1) & 0xFFFF0000u);
                }
                const int off = row * 32 + ((g ^ swz) << 3);
                *(uint4*)&Bh[off] = *(uint4*)hi;
                *(uint4*)&Bl[off] = *(uint4*)lo;
            }
        } else {
            const int n = tid & 127;
            const int swz = (n & 3) ^ ((n >> 2) & 3);
            #pragma unroll
            for (int gg = 0; gg < 2; ++gg) {
                const int g = ((tid >> 7) << 1) + gg;
                float v[8];
                #pragma unroll
                for (int e = 0; e < 8; ++e)
                    v[e] = B[(long)(k0 + (g << 3) + e) * 512 + n0 + n];
                unsigned hi[4], lo[4];
                #pragma unroll
                for (int qq = 0; qq < 4; ++qq) {
                    const unsigned b0 = __float_as_uint(v[2 * qq])     & 0xFFFF0000u;
                    const unsigned b1 = __float_as_uint(v[2 * qq + 1]) & 0xFFFF0000u;
                    const float d0 = v[2 * qq]     - __uint_as_float(b0);
                    const float d1 = v[2 * qq + 1] - __uint_as_float(b1);
                    hi[qq] = (b0 >> 16) | b1;
                    lo[qq] = (__float_as_uint(d0) >> 16) | (__float_as_uint(d1) & 0xFFFF0000u);
                }
                const int off = n * 32 + ((g ^ swz) << 3);
                *(uint4*)&Bh[off] = *(uint4*)hi;
                *(uint4*)&Bl[off] = *(uint4*)lo;
            }
        }
        __syncthreads();

        {
            const int r = lane & 15, g = lane >> 4;
            const int lswz = (r & 3) ^ ((r >> 2) & 3);
            const int gslot = ((g ^ lswz) << 3);
            const int abase = ((wr << 6) + r) * 32 + gslot;
            const int bbase = ((wc << 6) + r) * 32 + gslot;
            short8v afh[4], afl[4], bfh[4], bfl[4];
            #pragma unroll
            for (int f = 0; f < 4; ++f) {
                afh[f] = *(short8v*)&Ah[abase + f * 512];
                afl[f] = *(short8v*)&Al[abase + f * 512];
                bfh[f] = *(short8v*)&Bh[bbase + f * 512];
                bfl[f] = *(short8v*)&Bl[bbase + f * 512];
            }
            #pragma unroll
            for (int fi = 0; fi < 4; ++fi)
                #pragma unroll
                for (int fj = 0; fj < 4; ++fj) {
                    acc[fi][fj] = __builtin_amdgcn_mfma_f32_16x16x32_bf16(
                        afh[fi], bfh[fj], acc[fi][fj], 0, 0, 0);
                    acc[fi][fj] = __builtin_amdgcn_mfma_f32_16x16x32_bf16(
                        afh[fi], bfl[fj], acc[fi][fj], 0, 0, 0);
                    acc[fi][fj] = __builtin_amdgcn_mfma_f32_16x16x32_bf16(
                        afl[fi], bfh[fj], acc[fi][fj], 0, 0, 0);
                }
        }
        __syncthreads();
    }

    const int r = lane & 15, g = lane >> 4;
    #pragma unroll
    for (int fi = 0; fi < 4; ++fi) {
        const int gr0 = m0 + (wr << 6) + fi * 16 + g * 4;
        #pragma unroll
        for (int fj = 0; fj < 4; ++fj) {
            const int gc = n0 + (wc << 6) + fj * 16 + r;
            #pragma unroll
            for (int qq = 0; qq < 4; ++qq)
                C[(long)(gr0 + qq) * 512 + gc] = acc[fi][fj][qq] * scale;
        }
    }
}

// ---------------------------------------------------------------------------
// Row softmax over 512, in place.
// ---------------------------------------------------------------------------
__global__ __launch_bounds__(256)
void softmax_kernel(float* __restrict__ P)
{
    float* p = P + (long)blockIdx.x * 512;
    const int t = threadIdx.x;
    float v0 = p[t], v1 = p[t + 256];
    __shared__ float red[256];
    red[t] = fmaxf(v0, v1);
    __syncthreads();
    #pragma unroll
    for (int s = 128; s > 0; s >>= 1) {
        if (t < s) red[t] = fmaxf(red[t], red[t + s]);
        __syncthreads();
    }
    const float mx = red[0];
    __syncthreads();
    const float e0 = __expf(v0 - mx), e1 = __expf(v1 - mx);
    red[t] = e0 + e1;
    __syncthreads();
    #pragma unroll
    for (int s = 128; s > 0; s >>= 1) {
        if (t < s) red[t] += red[t + s];
        __syncthreads();
    }
    const float inv = 1.0f / red[0];
    p[t] = e0 * inv;
    p[t + 256] = e1 * inv;
}

// ---------------------------------------------------------------------------
// O = P @ V per head: M=512, N=64, K=512.
// ---------------------------------------------------------------------------
__global__ __launch_bounds__(256)
void gemm_pv(const float* __restrict__ P, const float* __restrict__ V,
             float* __restrict__ O)
{
    const int bh = blockIdx.z;
    const float* Pp = P + (long)bh * 262144;
    const float* Vp = V + (long)bh * 32768;
    float* Op = O + (long)bh * 32768;

    __shared__ float Ps[16][68];
    __shared__ float Vs[16][68];

    const int tid = threadIdx.x;
    const int tx = tid & 15, ty = tid >> 4;
    const int m0 = blockIdx.y << 6;

    float acc[4][4] = {};

    for (int k0 = 0; k0 < 512; k0 += 16) {
        const int r = tid >> 2, c4 = (tid & 3) << 2;
        float4 av = *(const float4*)(Pp + (long)(m0 + r) * 512 + k0 + c4);
        const int rb = tid >> 4, cb = (tid & 15) << 2;
        float4 bv = *(const float4*)(Vp + (long)(k0 + rb) * 64 + cb);

        Ps[c4 + 0][r] = av.x; Ps[c4 + 1][r] = av.y;
        Ps[c4 + 2][r] = av.z; Ps[c4 + 3][r] = av.w;
        *(float4*)&Vs[rb][cb] = bv;
        __syncthreads();

        #pragma unroll
        for (int kk = 0; kk < 16; ++kk) {
            float a[4], b[4];
            *(float4*)a = *(const float4*)&Ps[kk][ty << 2];
            *(float4*)b = *(const float4*)&Vs[kk][tx << 2];
            #pragma unroll
            for (int i = 0; i < 4; ++i)
                #pragma unroll
                for (int j = 0; j < 4; ++j)
                    acc[i][j] = fmaf(a[i], b[j], acc[i][j]);
        }
        __syncthreads();
    }

    #pragma unroll
    for (int i = 0; i < 4; ++i) {
        float4 v = make_float4(acc[i][0], acc[i][1], acc[i][2], acc[i][3]);
        *(float4*)(Op + (long)(m0 + (ty << 2) + i) * 64 + (tx << 2)) = v;
    }
}

// ---------------------------------------------------------------------------
// Transpose O [BH][L][HD] -> Of [B][L][H*HD]
// ---------------------------------------------------------------------------
__global__ __launch_bounds__(256)
void transO_kernel(const float* __restrict__ O, float* __restrict__ Of)
{
    const long i4 = ((long)blockIdx.x * 256 + threadIdx.x) << 2;
    const int d = (int)(i4 & 63);
    const long rest = i4 >> 6;
    const int l = (int)(rest & 511);
    const long bh = rest >> 9;
    const int h = (int)(bh & 7);
    const long b = bh >> 3;
    const float4 v = *(const float4*)(O + i4);
    *(float4*)(Of + (((b << 9) + l) << 9) + (h << 6) + d) = v;
}

// ---------------------------------------------------------------------------
extern "C" void kernel_launch(void* const* d_in, const int* in_sizes, int n_in,
                              void* d_out, int out_size, void* d_ws, size_t ws_size,
                              hipStream_t stream)
{
    const float* x  = (const float*)d_in[0];
    const float* Wq = (const float*)d_in[1];
    const float* Wk = (const float*)d_in[2];
    const float* Wv = (const float*)d_in[3];
    const float* Wo = (const float*)d_in[4];
    float* out = (float*)d_out;

    float* ws = (float*)d_ws;
    float* Q  = ws;                       // 1M floats (QKV base)
    float* Kt = Q  + (1u << 20);          // 1M
    float* V  = Kt + (1u << 20);          // 1M
    float* S  = V  + (1u << 20);          // 8M
    float* Am = S  + (8u << 20);          // 8M (adjacency -> A_hat)
    float* T  = Am + (8u << 20);          // 8M (A_hat@S temp)
    float* R  = T  + (8u << 20);          // 16K
    float* O  = R  + 16384;               // 1M

    dim3 blk(256);

    // 1) fused QKV projections
    gemm_qkv<<<dim3(12, 16, 1), blk, 0, stream>>>(x, Wq, Wk, Wv, Q);

    // 2) S = Q K^T per head
    gemm128<1><<<dim3(4, 4, 32), blk, 0, stream>>>(Q, Kt, S, 512, 512, 64,
                                                   32768, 32768, 262144, 1.0f);

    // 3) adjacency (2-wave blocks, in-block j-split, mirrored symmetric write)
    adj_kernel<<<dim3(36, 32), dim3(128), 0, stream>>>(S, Am);

    // 4) row degrees -> R
    rowsum_kernel<<<dim3(4096), blk, 0, stream>>>(Am, R);

    // 5) A_hat in place
    ahat_kernel<<<dim3(8192), blk, 0, stream>>>(Am, R);

    // 6) T = A_hat @ S   (split-bf16 MFMA)
    gemm_mfma<0><<<dim3(4, 4, 32), blk, 0, stream>>>(Am, S, T, 1.0f);

    // 7) J = T @ A_hat^T / 8 -> S
    gemm_mfma<1><<<dim3(4, 4, 32), blk, 0, stream>>>(T, Am, S, 0.125f);

    // 8) softmax rows of J
    softmax_kernel<<<dim3(16384), blk, 0, stream>>>(S);

    // 9) O = P @ V
    gemm_pv<<<dim3(1, 8, 32), blk, 0, stream>>>(S, V, O);

    // 10) O -> Of (reuse Q)
    transO_kernel<<<dim3(1024), blk, 0, stream>>>(O, Q);

    // 11) out = Of @ Wo
    gemm128<0><<<dim3(4, 16, 1), blk, 0, stream>>>(Q, Wo, out, 2048, 512, 512,
                                                   0, 0, 0, 1.0f);
}

// Round 5
// 458.601 us; speedup vs baseline: 1.3719x; 1.3719x over previous
//
#include <hip/hip_runtime.h>
#include <math.h>

// Problem constants: B=4, H=8, L=512, HD=64, D=512, RHO=0.1
// Workspace (floats):
//   Q   : 1M   [BH][512][64]   (QKV base)
//   Kt  : 1M
//   V   : 1M
//   S   : 8M   [BH][512][512]  (scores -> later J -> softmax'd P)
//   Am  : 8M   (adjacency -> A_hat in place)
//   T   : 8M   (A_hat@S temp)
//   R   : 16K  (row inv-sqrt degrees)
//   O   : 1M

typedef __attribute__((ext_vector_type(8))) short short8v;
typedef __attribute__((ext_vector_type(4))) float f32x4;

// ---------------------------------------------------------------------------
// bf16 split helper: pack 8 fp32 -> hi/lo bf16x8 (truncation split)
// ---------------------------------------------------------------------------
__device__ __forceinline__ void split8(const float* v, unsigned* hi, unsigned* lo)
{
    #pragma unroll
    for (int q = 0; q < 4; ++q) {
        const unsigned b0 = __float_as_uint(v[2 * q])     & 0xFFFF0000u;
        const unsigned b1 = __float_as_uint(v[2 * q + 1]) & 0xFFFF0000u;
        const float d0 = v[2 * q]     - __uint_as_float(b0);
        const float d1 = v[2 * q + 1] - __uint_as_float(b1);
        hi[q] = (b0 >> 16) | b1;
        lo[q] = (__float_as_uint(d0) >> 16) | (__float_as_uint(d1) & 0xFFFF0000u);
    }
}

// ---------------------------------------------------------------------------
// Split-bf16 MFMA GEMM. 128x128 tile, 256 threads (4 waves 2x2), K-step 32.
// BT=0: C = A @ B; BT=1: C = A @ B^T. acc = Ahi*Bhi + Ahi*Blo + Alo*Bhi.
// Runtime K, lda, ldb, ldc, batch strides. Grid: (N/128, M/128, nbatch).
// ---------------------------------------------------------------------------
template<int BT>
__global__ __launch_bounds__(256)
void gemm_mfma(const float* __restrict__ Ap, const float* __restrict__ Bp,
               float* __restrict__ Cp, int K, int lda, int ldb, int ldc,
               long sA, long sB, long sC, float scale)
{
    const float* __restrict__ A = Ap + (long)blockIdx.z * sA;
    const float* __restrict__ B = Bp + (long)blockIdx.z * sB;
    float* __restrict__ C = Cp + (long)blockIdx.z * sC;
    const int m0 = blockIdx.y << 7, n0 = blockIdx.x << 7;

    __shared__ short Ah[128 * 32], Al[128 * 32], Bh[128 * 32], Bl[128 * 32];

    const int tid = threadIdx.x;
    const int lane = tid & 63, wv = tid >> 6;
    const int wr = wv >> 1, wc = wv & 1;

    f32x4 acc[4][4] = {};

    for (int k0 = 0; k0 < K; k0 += 32) {
        {
            const int row = tid >> 1;
            const int swz = (row & 3) ^ ((row >> 2) & 3);
            #pragma unroll
            for (int gg = 0; gg < 2; ++gg) {
                const int g = ((tid & 1) << 1) + gg;
                const float* src = A + (long)(m0 + row) * lda + k0 + (g << 3);
                float v[8];
                *(float4*)&v[0] = *(const float4*)src;
                *(float4*)&v[4] = *(const float4*)(src + 4);
                unsigned hi[4], lo[4];
                split8(v, hi, lo);
                const int off = row * 32 + ((g ^ swz) << 3);
                *(uint4*)&Ah[off] = *(uint4*)hi;
                *(uint4*)&Al[off] = *(uint4*)lo;
            }
        }
        if (BT) {
            const int row = tid >> 1;
            const int swz = (row & 3) ^ ((row >> 2) & 3);
            #pragma unroll
            for (int gg = 0; gg < 2; ++gg) {
                const int g = ((tid & 1) << 1) + gg;
                const float* src = B + (long)(n0 + row) * ldb + k0 + (g << 3);
                float v[8];
                *(float4*)&v[0] = *(const float4*)src;
                *(float4*)&v[4] = *(const float4*)(src + 4);
                unsigned hi[4], lo[4];
                split8(v, hi, lo);
                const int off = row * 32 + ((g ^ swz) << 3);
                *(uint4*)&Bh[off] = *(uint4*)hi;
                *(uint4*)&Bl[off] = *(uint4*)lo;
            }
        } else {
            const int n = tid & 127;
            const int swz = (n & 3) ^ ((n >> 2) & 3);
            #pragma unroll
            for (int gg = 0; gg < 2; ++gg) {
                const int g = ((tid >> 7) << 1) + gg;
                float v[8];
                #pragma unroll
                for (int e = 0; e < 8; ++e)
                    v[e] = B[(long)(k0 + (g << 3) + e) * ldb + n0 + n];
                unsigned hi[4], lo[4];
                split8(v, hi, lo);
                const int off = n * 32 + ((g ^ swz) << 3);
                *(uint4*)&Bh[off] = *(uint4*)hi;
                *(uint4*)&Bl[off] = *(uint4*)lo;
            }
        }
        __syncthreads();

        {
            const int r = lane & 15, g = lane >> 4;
            const int lswz = (r & 3) ^ ((r >> 2) & 3);
            const int gslot = ((g ^ lswz) << 3);
            const int abase = ((wr << 6) + r) * 32 + gslot;
            const int bbase = ((wc << 6) + r) * 32 + gslot;
            short8v afh[4], afl[4], bfh[4], bfl[4];
            #pragma unroll
            for (int f = 0; f < 4; ++f) {
                afh[f] = *(short8v*)&Ah[abase + f * 512];
                afl[f] = *(short8v*)&Al[abase + f * 512];
                bfh[f] = *(short8v*)&Bh[bbase + f * 512];
                bfl[f] = *(short8v*)&Bl[bbase + f * 512];
            }
            #pragma unroll
            for (int fi = 0; fi < 4; ++fi)
                #pragma unroll
                for (int fj = 0; fj < 4; ++fj) {
                    acc[fi][fj] = __builtin_amdgcn_mfma_f32_16x16x32_bf16(
                        afh[fi], bfh[fj], acc[fi][fj], 0, 0, 0);
                    acc[fi][fj] = __builtin_amdgcn_mfma_f32_16x16x32_bf16(
                        afh[fi], bfl[fj], acc[fi][fj], 0, 0, 0);
                    acc[fi][fj] = __builtin_amdgcn_mfma_f32_16x16x32_bf16(
                        afl[fi], bfh[fj], acc[fi][fj], 0, 0, 0);
                }
        }
        __syncthreads();
    }

    // C/D layout: col = lane&15, row = (lane>>4)*4 + reg  [m89/m91]
    const int r = lane & 15, g = lane >> 4;
    #pragma unroll
    for (int fi = 0; fi < 4; ++fi) {
        const int gr0 = m0 + (wr << 6) + fi * 16 + g * 4;
        #pragma unroll
        for (int fj = 0; fj < 4; ++fj) {
            const int gc = n0 + (wc << 6) + fj * 16 + r;
            #pragma unroll
            for (int qq = 0; qq < 4; ++qq)
                C[(long)(gr0 + qq) * ldc + gc] = acc[fi][fj][qq] * scale;
        }
    }
}

// ---------------------------------------------------------------------------
// Fused QKV projection via split-bf16 MFMA: x[2048x512] @ {Wq|Wk|Wv}[512x512]
// -> QKV [3][BH][512][64]. Grid (12, 16).
// ---------------------------------------------------------------------------
__global__ __launch_bounds__(256)
void gemm_qkv_mfma(const float* __restrict__ x, const float* __restrict__ Wq,
                   const float* __restrict__ Wk, const float* __restrict__ Wv,
                   float* __restrict__ QKV)
{
    const int m0 = blockIdx.y << 7;
    const int ng = blockIdx.x << 7;
    const float* __restrict__ W = (ng < 512) ? Wq : (ng < 1024) ? Wk : Wv;
    const int n0 = ng & 511;
    float* __restrict__ C = QKV + (long)(ng >> 9) * (1 << 20);

    __shared__ short Ah[128 * 32], Al[128 * 32], Bh[128 * 32], Bl[128 * 32];

    const int tid = threadIdx.x;
    const int lane = tid & 63, wv = tid >> 6;
    const int wr = wv >> 1, wc = wv & 1;

    f32x4 acc[4][4] = {};

    for (int k0 = 0; k0 < 512; k0 += 32) {
        {
            const int row = tid >> 1;
            const int swz = (row & 3) ^ ((row >> 2) & 3);
            #pragma unroll
            for (int gg = 0; gg < 2; ++gg) {
                const int g = ((tid & 1) << 1) + gg;
                const float* src = x + (long)(m0 + row) * 512 + k0 + (g << 3);
                float v[8];
                *(float4*)&v[0] = *(const float4*)src;
                *(float4*)&v[4] = *(const float4*)(src + 4);
                unsigned hi[4], lo[4];
                split8(v, hi, lo);
                const int off = row * 32 + ((g ^ swz) << 3);
                *(uint4*)&Ah[off] = *(uint4*)hi;
                *(uint4*)&Al[off] = *(uint4*)lo;
            }
        }
        {
            const int n = tid & 127;
            const int swz = (n & 3) ^ ((n >> 2) & 3);
            #pragma unroll
            for (int gg = 0; gg < 2; ++gg) {
                const int g = ((tid >> 7) << 1) + gg;
                float v[8];
                #pragma unroll
                for (int e = 0; e < 8; ++e)
                    v[e] = W[(long)(k0 + (g << 3) + e) * 512 + n0 + n];
                unsigned hi[4], lo[4];
                split8(v, hi, lo);
                const int off = n * 32 + ((g ^ swz) << 3);
                *(uint4*)&Bh[off] = *(uint4*)hi;
                *(uint4*)&Bl[off] = *(uint4*)lo;
            }
        }
        __syncthreads();

        {
            const int r = lane & 15, g = lane >> 4;
            const int lswz = (r & 3) ^ ((r >> 2) & 3);
            const int gslot = ((g ^ lswz) << 3);
            const int abase = ((wr << 6) + r) * 32 + gslot;
            const int bbase = ((wc << 6) + r) * 32 + gslot;
            short8v afh[4], afl[4], bfh[4], bfl[4];
            #pragma unroll
            for (int f = 0; f < 4; ++f) {
                afh[f] = *(short8v*)&Ah[abase + f * 512];
                afl[f] = *(short8v*)&Al[abase + f * 512];
                bfh[f] = *(short8v*)&Bh[bbase + f * 512];
                bfl[f] = *(short8v*)&Bl[bbase + f * 512];
            }
            #pragma unroll
            for (int fi = 0; fi < 4; ++fi)
                #pragma unroll
                for (int fj = 0; fj < 4; ++fj) {
                    acc[fi][fj] = __builtin_amdgcn_mfma_f32_16x16x32_bf16(
                        afh[fi], bfh[fj], acc[fi][fj], 0, 0, 0);
                    acc[fi][fj] = __builtin_amdgcn_mfma_f32_16x16x32_bf16(
                        afh[fi], bfl[fj], acc[fi][fj], 0, 0, 0);
                    acc[fi][fj] = __builtin_amdgcn_mfma_f32_16x16x32_bf16(
                        afl[fi], bfh[fj], acc[fi][fj], 0, 0, 0);
                }
        }
        __syncthreads();
    }

    // scatter epilogue: m=(b,l), n_local=(h,d)
    const int r = lane & 15, g = lane >> 4;
    #pragma unroll
    for (int fi = 0; fi < 4; ++fi) {
        const int gr0 = m0 + (wr << 6) + fi * 16 + g * 4;
        #pragma unroll
        for (int fj = 0; fj < 4; ++fj) {
            const int nl = n0 + (wc << 6) + fj * 16 + r;
            const int h = nl >> 6, d = nl & 63;
            #pragma unroll
            for (int qq = 0; qq < 4; ++qq) {
                const int m = gr0 + qq;
                const int b = m >> 9, l = m & 511;
                C[((long)((b * 8 + h) * 512 + l)) * 64 + d] = acc[fi][fj][qq];
            }
        }
    }
}

// ---------------------------------------------------------------------------
// Adjacency v4: A[i,k] = 2^-15 * sum_j (p = S_ij*S_kj) if p > 0.1*64, diag 0.
// (pow2 scaling commutes with fp rounding -> decisions/values match reference)
// 64x64 tile per block, upper-tri tile pairs (36), mirrored symmetric write.
// Block = 4 waves; wave wv sums j in [128*wv, 128*wv+128) with PRIVATE LDS
// staging (no barriers in main loop). 8x8 micro-tile per lane (64 chains).
// 3-phase LDS tree reduce combines wave partials; wave 0 finalizes.
// ---------------------------------------------------------------------------
__global__ __launch_bounds__(256)
void adj_kernel(const float* __restrict__ S, float* __restrict__ A)
{
    const int bh = blockIdx.y;
    const float* __restrict__ Sh = S + (long)bh * 262144;
    float* __restrict__ Ah = A + (long)bh * 262144;

    int ti = 0, rem = blockIdx.x;
    while (rem >= 8 - ti) { rem -= 8 - ti; ++ti; }
    const int tk = ti + rem;
    const int i0 = ti << 6, k0 = tk << 6;

    __shared__ float smem[8704];        // 34816 B: staging 4x(2x16x68) / reduce 2x(64x68)

    const int tid  = threadIdx.x;
    const int lane = tid & 63;
    const int wv   = tid >> 6;
    const int ly8  = (lane >> 3) << 3;
    const int lx8  = (lane & 7) << 3;
    const int r4   = lane >> 2;          // 0..15
    const int q    = lane & 3;           // 0..3

    float (*stgL)[68] = (float(*)[68])&smem[wv * 2176];
    float (*stgR)[68] = (float(*)[68])&smem[wv * 2176 + 1088];

    const float RHO64 = 0.1f * 64.0f;

    float acc[8][8] = {};

    const int jw = wv << 7;              // this wave's j base
    for (int c = 0; c < 8; ++c) {
        const int j0 = jw + (c << 4);
        float4 rl[4], rr[4];
        #pragma unroll
        for (int p = 0; p < 4; ++p) {
            rl[p] = *(const float4*)(Sh + (long)(i0 + r4 + (p << 4)) * 512 + j0 + (q << 2));
            rr[p] = *(const float4*)(Sh + (long)(k0 + r4 + (p << 4)) * 512 + j0 + (q << 2));
        }
        #pragma unroll
        for (int p = 0; p < 4; ++p) {
            const int row = r4 + (p << 4);
            stgL[(q << 2) + 0][row] = rl[p].x;
            stgL[(q << 2) + 1][row] = rl[p].y;
            stgL[(q << 2) + 2][row] = rl[p].z;
            stgL[(q << 2) + 3][row] = rl[p].w;
            stgR[(q << 2) + 0][row] = rr[p].x;
            stgR[(q << 2) + 1][row] = rr[p].y;
            stgR[(q << 2) + 2][row] = rr[p].z;
            stgR[(q << 2) + 3][row] = rr[p].w;
        }
        // wave-private staging: only need LDS-op completion, no barrier
        __builtin_amdgcn_s_waitcnt(0);   // lgkmcnt(0)+vmcnt(0) conservative drain
        #pragma unroll 4
        for (int jj = 0; jj < 16; ++jj) {
            float a[8], b[8];
            *(float4*)&a[0] = *(const float4*)&stgL[jj][ly8];
            *(float4*)&a[4] = *(const float4*)&stgL[jj][ly8 + 4];
            *(float4*)&b[0] = *(const float4*)&stgR[jj][lx8];
            *(float4*)&b[4] = *(const float4*)&stgR[jj][lx8 + 4];
            #pragma unroll
            for (int i = 0; i < 8; ++i)
                #pragma unroll
                for (int j = 0; j < 8; ++j) {
                    const float u = a[i] * b[j];
                    if (u > RHO64) acc[i][j] += u;
                }
        }
    }

    // ---- 3-phase reduce: (w0+w1) + (w3+w2), result in wave 0 ----
    float* red0 = &smem[0];
    float* red1 = &smem[4352];

    __syncthreads();
    if (wv == 1 || wv == 2) {
        float* dst = (wv == 1 ? red0 : red1) + lane * 68;
        #pragma unroll
        for (int i = 0; i < 8; ++i) {
            *(float4*)(dst + i * 8)     = *(float4*)&acc[i][0];
            *(float4*)(dst + i * 8 + 4) = *(float4*)&acc[i][4];
        }
    }
    __syncthreads();
    if (wv == 0 || wv == 3) {
        const float* src = (wv == 0 ? red0 : red1) + lane * 68;
        #pragma unroll
        for (int i = 0; i < 8; ++i) {
            float4 p0 = *(const float4*)(src + i * 8);
            float4 p1 = *(const float4*)(src + i * 8 + 4);
            acc[i][0] += p0.x; acc[i][1] += p0.y; acc[i][2] += p0.z; acc[i][3] += p0.w;
            acc[i][4] += p1.x; acc[i][5] += p1.y; acc[i][6] += p1.z; acc[i][7] += p1.w;
        }
    }
    __syncthreads();
    if (wv == 3) {
        float* dst = red0 + lane * 68;
        #pragma unroll
        for (int i = 0; i < 8; ++i) {
            *(float4*)(dst + i * 8)     = *(float4*)&acc[i][0];
            *(float4*)(dst + i * 8 + 4) = *(float4*)&acc[i][4];
        }
    }
    __syncthreads();
    if (wv == 0) {
        const float* src = red0 + lane * 68;
        const float SC = 1.0f / 32768.0f;    // 2^-15 exact
        float f[8][8];
        #pragma unroll
        for (int i = 0; i < 8; ++i) {
            float4 p0 = *(const float4*)(src + i * 8);
            float4 p1 = *(const float4*)(src + i * 8 + 4);
            f[i][0] = (acc[i][0] + p0.x) * SC;
            f[i][1] = (acc[i][1] + p0.y) * SC;
            f[i][2] = (acc[i][2] + p0.z) * SC;
            f[i][3] = (acc[i][3] + p0.w) * SC;
            f[i][4] = (acc[i][4] + p1.x) * SC;
            f[i][5] = (acc[i][5] + p1.y) * SC;
            f[i][6] = (acc[i][6] + p1.z) * SC;
            f[i][7] = (acc[i][7] + p1.w) * SC;
        }
        if (ti == tk) {
            #pragma unroll
            for (int i = 0; i < 8; ++i)
                #pragma unroll
                for (int j = 0; j < 8; ++j)
                    if (ly8 + i == lx8 + j) f[i][j] = 0.0f;
        }
        #pragma unroll
        for (int i = 0; i < 8; ++i) {
            float* dst = Ah + (long)(i0 + ly8 + i) * 512 + k0 + lx8;
            *(float4*)dst       = make_float4(f[i][0], f[i][1], f[i][2], f[i][3]);
            *(float4*)(dst + 4) = make_float4(f[i][4], f[i][5], f[i][6], f[i][7]);
        }
        if (ti != tk) {
            #pragma unroll
            for (int j = 0; j < 8; ++j) {
                float* dst = Ah + (long)(k0 + lx8 + j) * 512 + i0 + ly8;
                *(float4*)dst       = make_float4(f[0][j], f[1][j], f[2][j], f[3][j]);
                *(float4*)(dst + 4) = make_float4(f[4][j], f[5][j], f[6][j], f[7][j]);
            }
        }
    }
}

// ---------------------------------------------------------------------------
// Row degree: R[row] = 1/sqrt(clip(1 + sum_k A[row,k], 1e-6))
// ---------------------------------------------------------------------------
__global__ __launch_bounds__(256)
void rowsum_kernel(const float* __restrict__ A, float* __restrict__ R)
{
    const int row = (blockIdx.x << 2) + (threadIdx.x >> 6);
    const int lane = threadIdx.x & 63;
    const float* p = A + (long)row * 512;
    float s = 0.0f;
    #pragma unroll
    for (int t = 0; t < 8; ++t) s += p[lane + (t << 6)];
    #pragma unroll
    for (int off = 32; off; off >>= 1) s += __shfl_xor(s, off, 64);
    if (lane == 0) R[row] = 1.0f / sqrtf(fmaxf(1.0f + s, 1e-6f));
}

// ---------------------------------------------------------------------------
// A_hat[i,k] = R[i]*R[k]*(A[i,k] + (i==k)) in place
// ---------------------------------------------------------------------------
__global__ __launch_bounds__(256)
void ahat_kernel(float* __restrict__ A, const float* __restrict__ R)
{
    const long i4 = ((long)blockIdx.x * 256 + threadIdx.x) << 2;
    const long off = i4 & 262143;
    const long bh = i4 >> 18;
    const int i = (int)(off >> 9);
    const int k = (int)(off & 511);
    const float ri = R[(bh << 9) + i];
    const float* Rk = R + (bh << 9) + k;
    float4 v = *(float4*)(A + i4);
    v.x = ri * Rk[0] * (v.x + ((k + 0) == i ? 1.0f : 0.0f));
    v.y = ri * Rk[1] * (v.y + ((k + 1) == i ? 1.0f : 0.0f));
    v.z = ri * Rk[2] * (v.z + ((k + 2) == i ? 1.0f : 0.0f));
    v.w = ri * Rk[3] * (v.w + ((k + 3) == i ? 1.0f : 0.0f));
    *(float4*)(A + i4) = v;
}

// ---------------------------------------------------------------------------
// Row softmax over 512, in place.
// ---------------------------------------------------------------------------
__global__ __launch_bounds__(256)
void softmax_kernel(float* __restrict__ P)
{
    float* p = P + (long)blockIdx.x * 512;
    const int t = threadIdx.x;
    float v0 = p[t], v1 = p[t + 256];
    __shared__ float red[256];
    red[t] = fmaxf(v0, v1);
    __syncthreads();
    #pragma unroll
    for (int s = 128; s > 0; s >>= 1) {
        if (t < s) red[t] = fmaxf(red[t], red[t + s]);
        __syncthreads();
    }
    const float mx = red[0];
    __syncthreads();
    const float e0 = __expf(v0 - mx), e1 = __expf(v1 - mx);
    red[t] = e0 + e1;
    __syncthreads();
    #pragma unroll
    for (int s = 128; s > 0; s >>= 1) {
        if (t < s) red[t] += red[t + s];
        __syncthreads();
    }
    const float inv = 1.0f / red[0];
    p[t] = e0 * inv;
    p[t + 256] = e1 * inv;
}

// ---------------------------------------------------------------------------
// O = P @ V per head: M=512, N=64, K=512. fp32, 64x64 tile, 4x4 micro.
// ---------------------------------------------------------------------------
__global__ __launch_bounds__(256)
void gemm_pv(const float* __restrict__ P, const float* __restrict__ V,
             float* __restrict__ O)
{
    const int bh = blockIdx.z;
    const float* Pp = P + (long)bh * 262144;
    const float* Vp = V + (long)bh * 32768;
    float* Op = O + (long)bh * 32768;

    __shared__ float Ps[16][68];
    __shared__ float Vs[16][68];

    const int tid = threadIdx.x;
    const int tx = tid & 15, ty = tid >> 4;
    const int m0 = blockIdx.y << 6;

    float acc[4][4] = {};

    for (int k0 = 0; k0 < 512; k0 += 16) {
        const int r = tid >> 2, c4 = (tid & 3) << 2;
        float4 av = *(const float4*)(Pp + (long)(m0 + r) * 512 + k0 + c4);
        const int rb = tid >> 4, cb = (tid & 15) << 2;
        float4 bv = *(const float4*)(Vp + (long)(k0 + rb) * 64 + cb);

        Ps[c4 + 0][r] = av.x; Ps[c4 + 1][r] = av.y;
        Ps[c4 + 2][r] = av.z; Ps[c4 + 3][r] = av.w;
        *(float4*)&Vs[rb][cb] = bv;
        __syncthreads();

        #pragma unroll
        for (int kk = 0; kk < 16; ++kk) {
            float a[4], b[4];
            *(float4*)a = *(const float4*)&Ps[kk][ty << 2];
            *(float4*)b = *(const float4*)&Vs[kk][tx << 2];
            #pragma unroll
            for (int i = 0; i < 4; ++i)
                #pragma unroll
                for (int j = 0; j < 4; ++j)
                    acc[i][j] = fmaf(a[i], b[j], acc[i][j]);
        }
        __syncthreads();
    }

    #pragma unroll
    for (int i = 0; i < 4; ++i) {
        float4 v = make_float4(acc[i][0], acc[i][1], acc[i][2], acc[i][3]);
        *(float4*)(Op + (long)(m0 + (ty << 2) + i) * 64 + (tx << 2)) = v;
    }
}

// ---------------------------------------------------------------------------
// Transpose O [BH][L][HD] -> Of [B][L][H*HD]
// ---------------------------------------------------------------------------
__global__ __launch_bounds__(256)
void transO_kernel(const float* __restrict__ O, float* __restrict__ Of)
{
    const long i4 = ((long)blockIdx.x * 256 + threadIdx.x) << 2;
    const int d = (int)(i4 & 63);
    const long rest = i4 >> 6;
    const int l = (int)(rest & 511);
    const long bh = rest >> 9;
    const int h = (int)(bh & 7);
    const long b = bh >> 3;
    const float4 v = *(const float4*)(O + i4);
    *(float4*)(Of + (((b << 9) + l) << 9) + (h << 6) + d) = v;
}

// ---------------------------------------------------------------------------
extern "C" void kernel_launch(void* const* d_in, const int* in_sizes, int n_in,
                              void* d_out, int out_size, void* d_ws, size_t ws_size,
                              hipStream_t stream)
{
    const float* x  = (const float*)d_in[0];
    const float* Wq = (const float*)d_in[1];
    const float* Wk = (const float*)d_in[2];
    const float* Wv = (const float*)d_in[3];
    const float* Wo = (const float*)d_in[4];
    float* out = (float*)d_out;

    float* ws = (float*)d_ws;
    float* Q  = ws;                       // 1M floats (QKV base)
    float* Kt = Q  + (1u << 20);          // 1M
    float* V  = Kt + (1u << 20);          // 1M
    float* S  = V  + (1u << 20);          // 8M
    float* Am = S  + (8u << 20);          // 8M (adjacency -> A_hat)
    float* T  = Am + (8u << 20);          // 8M (A_hat@S temp)
    float* R  = T  + (8u << 20);          // 16K
    float* O  = R  + 16384;               // 1M

    dim3 blk(256);

    // 1) fused QKV projections (split-bf16 MFMA)
    gemm_qkv_mfma<<<dim3(12, 16, 1), blk, 0, stream>>>(x, Wq, Wk, Wv, Q);

    // 2) S = Q K^T per head (MFMA, K=64)
    gemm_mfma<1><<<dim3(4, 4, 32), blk, 0, stream>>>(Q, Kt, S, 64, 64, 64, 512,
                                                     32768, 32768, 262144, 1.0f);

    // 3) adjacency (4-wave blocks, in-block j-split x4, 8x8 micro, mirror write)
    adj_kernel<<<dim3(36, 32), blk, 0, stream>>>(S, Am);

    // 4) row degrees -> R
    rowsum_kernel<<<dim3(4096), blk, 0, stream>>>(Am, R);

    // 5) A_hat in place
    ahat_kernel<<<dim3(8192), blk, 0, stream>>>(Am, R);

    // 6) T = A_hat @ S (MFMA)
    gemm_mfma<0><<<dim3(4, 4, 32), blk, 0, stream>>>(Am, S, T, 512, 512, 512, 512,
                                                     262144, 262144, 262144, 1.0f);

    // 7) J = T @ A_hat^T / 8 -> S (MFMA)
    gemm_mfma<1><<<dim3(4, 4, 32), blk, 0, stream>>>(T, Am, S, 512, 512, 512, 512,
                                                     262144, 262144, 262144, 0.125f);

    // 8) softmax rows of J
    softmax_kernel<<<dim3(16384), blk, 0, stream>>>(S);

    // 9) O = P @ V
    gemm_pv<<<dim3(1, 8, 32), blk, 0, stream>>>(S, V, O);

    // 10) O -> Of (reuse Q)
    transO_kernel<<<dim3(1024), blk, 0, stream>>>(O, Q);

    // 11) out = Of @ Wo (MFMA)
    gemm_mfma<0><<<dim3(4, 16, 1), blk, 0, stream>>>(Q, Wo, out, 512, 512, 512, 512,
                                                     0, 0, 0, 1.0f);
}